// Round 1
// baseline (336.800 us; speedup 1.0000x reference)
//
#include <hip/hip_runtime.h>

// DeepPoly ReLU relaxation — purely elementwise, memory-bound.
// Traffic: 6 fp32 streams x 16M elems = 402.7 MB -> ~64 us at 6.3 TB/s.

__device__ __forceinline__ void relax1(float x, float l, float h,
                                       float& xo, float& lo, float& ho) {
    bool crossing = (l < 0.0f) && (h > 0.0f);
    bool inactive = (h <= 0.0f);
    float denom   = crossing ? (h - l) : 1.0f;           // safe_denom
    float ub_slope = crossing ? (h / denom) : (inactive ? 0.0f : 1.0f);
    float ub_int   = crossing ? (-(l * h) / denom) : 0.0f;
    float lamda    = (l * l > h * h) ? 0.0f : 1.0f;
    float lb_slope = crossing ? lamda : (inactive ? 0.0f : 1.0f);
    xo = fmaxf(x, 0.0f);
    ho = ub_slope * h + ub_int;
    lo = lb_slope * l;
}

__global__ __launch_bounds__(256) void abstract_relu_kernel(
        const float4* __restrict__ x,
        const float4* __restrict__ low,
        const float4* __restrict__ high,
        float4* __restrict__ x_out,
        float4* __restrict__ low_out,
        float4* __restrict__ high_out,
        int n4) {
    int i = blockIdx.x * blockDim.x + threadIdx.x;
    if (i >= n4) return;

    float4 xv = x[i];
    float4 lv = low[i];
    float4 hv = high[i];
    float4 xr, lr, hr;

    relax1(xv.x, lv.x, hv.x, xr.x, lr.x, hr.x);
    relax1(xv.y, lv.y, hv.y, xr.y, lr.y, hr.y);
    relax1(xv.z, lv.z, hv.z, xr.z, lr.z, hr.z);
    relax1(xv.w, lv.w, hv.w, xr.w, lr.w, hr.w);

    x_out[i]    = xr;
    low_out[i]  = lr;
    high_out[i] = hr;
}

extern "C" void kernel_launch(void* const* d_in, const int* in_sizes, int n_in,
                              void* d_out, int out_size, void* d_ws, size_t ws_size,
                              hipStream_t stream) {
    const int n = in_sizes[0];          // 16777216, divisible by 4
    const int n4 = n / 4;

    const float4* x    = (const float4*)d_in[0];
    const float4* low  = (const float4*)d_in[1];
    const float4* high = (const float4*)d_in[2];

    float* out = (float*)d_out;         // [relu(x) | low_out | high_out]
    float4* x_out    = (float4*)(out);
    float4* low_out  = (float4*)(out + (size_t)n);
    float4* high_out = (float4*)(out + (size_t)2 * n);

    const int block = 256;
    const int grid  = (n4 + block - 1) / block;
    abstract_relu_kernel<<<grid, block, 0, stream>>>(
        x, low, high, x_out, low_out, high_out, n4);
}

// Round 4
// 320.621 us; speedup vs baseline: 1.0505x; 1.0505x over previous
//
#include <hip/hip_runtime.h>

// DeepPoly ReLU relaxation — purely elementwise, memory-bound.
// Traffic: 6 fp32 streams x 16M elems = 402.7 MB -> ~64 us floor at 6.3 TB/s.
// R1: top-5 rocprof dispatches are all 121us harness poison-fills; our kernel
// is below them (<121us). R2: __builtin_nontemporal_* needs a clang
// ext_vector_type. R3 fix: ext-vector elements can't bind to references —
// go through scalar temps + subscript assignment.

typedef float f32x4 __attribute__((ext_vector_type(4)));

__device__ __forceinline__ void relax1(float x, float l, float h,
                                       float& xo, float& lo, float& ho) {
    bool crossing = (l < 0.0f) && (h > 0.0f);
    bool inactive = (h <= 0.0f);
    // crossing => h>0, l<0 => h-l > 0. Speculative rcp; selected away otherwise.
    float inv = __builtin_amdgcn_rcpf(h - l);
    float ub_slope = crossing ? (h * inv) : (inactive ? 0.0f : 1.0f);
    float ub_int   = crossing ? (-(l * h) * inv) : 0.0f;
    float lamda    = (l * l > h * h) ? 0.0f : 1.0f;
    float lb_slope = crossing ? lamda : (inactive ? 0.0f : 1.0f);
    xo = fmaxf(x, 0.0f);
    ho = ub_slope * h + ub_int;
    lo = lb_slope * l;
}

__device__ __forceinline__ void relax4(f32x4 xv, f32x4 lv, f32x4 hv,
                                       f32x4& xr, f32x4& lr, f32x4& hr) {
#pragma unroll
    for (int j = 0; j < 4; ++j) {
        float xo, lo, ho;
        relax1(xv[j], lv[j], hv[j], xo, lo, ho);
        xr[j] = xo;
        lr[j] = lo;
        hr[j] = ho;
    }
}

__global__ __launch_bounds__(256) void abstract_relu_kernel(
        const f32x4* __restrict__ x,
        const f32x4* __restrict__ low,
        const f32x4* __restrict__ high,
        f32x4* __restrict__ x_out,
        f32x4* __restrict__ low_out,
        f32x4* __restrict__ high_out) {
    // Each block handles 512 float4s: lanes cover [base, base+256) and
    // [base+256, base+512) — both halves fully coalesced.
    int base = blockIdx.x * 512 + threadIdx.x;
    int i0 = base;
    int i1 = base + 256;

    f32x4 xv0 = __builtin_nontemporal_load(&x[i0]);
    f32x4 lv0 = __builtin_nontemporal_load(&low[i0]);
    f32x4 hv0 = __builtin_nontemporal_load(&high[i0]);
    f32x4 xv1 = __builtin_nontemporal_load(&x[i1]);
    f32x4 lv1 = __builtin_nontemporal_load(&low[i1]);
    f32x4 hv1 = __builtin_nontemporal_load(&high[i1]);

    f32x4 xr0, lr0, hr0, xr1, lr1, hr1;
    relax4(xv0, lv0, hv0, xr0, lr0, hr0);
    relax4(xv1, lv1, hv1, xr1, lr1, hr1);

    __builtin_nontemporal_store(xr0, &x_out[i0]);
    __builtin_nontemporal_store(lr0, &low_out[i0]);
    __builtin_nontemporal_store(hr0, &high_out[i0]);
    __builtin_nontemporal_store(xr1, &x_out[i1]);
    __builtin_nontemporal_store(lr1, &low_out[i1]);
    __builtin_nontemporal_store(hr1, &high_out[i1]);
}

extern "C" void kernel_launch(void* const* d_in, const int* in_sizes, int n_in,
                              void* d_out, int out_size, void* d_ws, size_t ws_size,
                              hipStream_t stream) {
    const int n = in_sizes[0];          // 16777216 = 2^24, divisible by 2048
    const int n4 = n / 4;               // float4 count

    const f32x4* x    = (const f32x4*)d_in[0];
    const f32x4* low  = (const f32x4*)d_in[1];
    const f32x4* high = (const f32x4*)d_in[2];

    float* out = (float*)d_out;         // [relu(x) | low_out | high_out]
    f32x4* x_out    = (f32x4*)(out);
    f32x4* low_out  = (f32x4*)(out + (size_t)n);
    f32x4* high_out = (f32x4*)(out + (size_t)2 * n);

    const int block = 256;
    const int grid  = n4 / 512;         // 8192 blocks, 512 float4s per block
    abstract_relu_kernel<<<grid, block, 0, stream>>>(
        x, low, high, x_out, low_out, high_out);
}